// Round 1
// 311.317 us; speedup vs baseline: 1.3071x; 1.3071x over previous
//
#include <hip/hip_runtime.h>
#include <hip/hip_bf16.h>

// GCNII fused, bf16 pre-scaled activations (xs = dinv*x), src-only CSR built by
// two-pass bucket sort, 4-node-slot gather waves with 8-edge-deep load pipelining,
// degree-sorted node permutation. N=100000, E=1000000, F=64.
// This version: per-tile 64x64 matmul moved to MFMA 16x16x32 bf16 with bf16x3
// (hi+lo split) precision compensation; W fragments pre-staged in LDS in
// fragment order; last layer fuses the GCNConv GEMM (mm_kernel eliminated).
// Output: concat(out1 [N*4], out2 [N*3], h [N*64]) fp32.
// NOTE: record packing (dst&127)<<17 | src requires N <= 131072.

#define TPB 256
#define NBSH 7    // 128 nodes per bucket
typedef __hip_bfloat16 bf16;
typedef __attribute__((ext_vector_type(8))) short short8;  // 8 bf16 = 4 VGPR
typedef __attribute__((ext_vector_type(4))) float f32x4;   // MFMA C/D frag

#define MFMA16(A, B, C) __builtin_amdgcn_mfma_f32_16x16x32_bf16((A), (B), (C), 0, 0, 0)

__device__ __forceinline__ float lo16(int u) { return __int_as_float(u << 16); }
__device__ __forceinline__ float hi16(int u) { return __int_as_float(u & 0xffff0000); }

// fp32 -> bf16 bits, round-to-nearest-even (finite inputs only)
__device__ __forceinline__ unsigned f2bfu(float f) {
    unsigned x = __float_as_uint(f);
    return ((x + 0x7fffu + ((x >> 16) & 1u)) >> 16) & 0xffffu;
}

// ---- pass 0: bucket histogram (LDS-privatized) ----
__global__ void ebhist_kernel(const int* __restrict__ col, int* __restrict__ bh,
                              int E, int B) {
    __shared__ int lh[800];
    for (int i = threadIdx.x; i < B; i += blockDim.x) lh[i] = 0;
    __syncthreads();
    for (int e = blockIdx.x * blockDim.x + threadIdx.x; e < E; e += gridDim.x * blockDim.x)
        atomicAdd(&lh[col[e] >> NBSH], 1);
    __syncthreads();
    for (int i = threadIdx.x; i < B; i += blockDim.x) {
        int c = lh[i];
        if (c) atomicAdd(&bh[i], c);
    }
}

// ---- exclusive scan of bh -> bcur (cursors) and boff (bounds, boff[B]=E) ----
__global__ void bscan_kernel(const int* __restrict__ bh, int* __restrict__ bcur,
                             int* __restrict__ boff, int B, int E) {
    __shared__ int s[256];
    int t = threadIdx.x;
    int v[4]; int sum = 0;
#pragma unroll
    for (int i = 0; i < 4; ++i) {
        int idx = t * 4 + i;
        v[i] = (idx < B) ? bh[idx] : 0;
        sum += v[i];
    }
    s[t] = sum;
    __syncthreads();
    for (int off = 1; off < 256; off <<= 1) {
        int val = (t >= off) ? s[t - off] : 0;
        __syncthreads();
        s[t] += val;
        __syncthreads();
    }
    int run = s[t] - sum;
#pragma unroll
    for (int i = 0; i < 4; ++i) {
        int idx = t * 4 + i;
        if (idx < B) { bcur[idx] = run; boff[idx] = run; }
        run += v[i];
    }
    if (t == 255) boff[B] = E;
}

// ---- pass 1: bucket scatter with per-block range reservation ----
__global__ void bucket_scatter_kernel(const int* __restrict__ ei, int* __restrict__ bcur,
                                      unsigned int* __restrict__ ebuf, int E, int B) {
    __shared__ int lh[800], lb[800];
    int chunk = (E + gridDim.x - 1) / gridDim.x;
    int beg = blockIdx.x * chunk;
    int end = min(beg + chunk, E);
    for (int i = threadIdx.x; i < B; i += blockDim.x) lh[i] = 0;
    __syncthreads();
    for (int e = beg + threadIdx.x; e < end; e += blockDim.x)
        atomicAdd(&lh[ei[E + e] >> NBSH], 1);
    __syncthreads();
    for (int i = threadIdx.x; i < B; i += blockDim.x) {
        int c = lh[i];
        lb[i] = c ? atomicAdd(&bcur[i], c) : 0;   // one global atomic per bin per block
    }
    __syncthreads();
    for (int i = threadIdx.x; i < B; i += blockDim.x) lh[i] = 0;
    __syncthreads();
    for (int e = beg + threadIdx.x; e < end; e += blockDim.x) {
        int r = ei[e];
        int c = ei[E + e];
        int bin = c >> NBSH;
        int rank = atomicAdd(&lh[bin], 1);        // LDS rank
        ebuf[lb[bin] + rank] = ((unsigned)(c & 127) << 17) | (unsigned)r;
    }
}

// ---- pass 2: per-bucket place; also emits degi/rowptr/dinv/sdeg ----
__global__ __launch_bounds__(128) void bucket_place_kernel(
        const int* __restrict__ boff, const unsigned int* __restrict__ ebuf,
        int* __restrict__ rowptr, int* __restrict__ degi,
        float* __restrict__ dinv, float* __restrict__ sdeg,
        int* __restrict__ srcids, int n) {
    __shared__ int cnt[128], loff[128], lcur[128];
    int b = blockIdx.x;
    int t = threadIdx.x;
    int lo = boff[b];
    int hi = boff[b + 1];
    int vbase = b << NBSH;
    cnt[t] = 0;
    __syncthreads();
    for (int i = lo + t; i < hi; i += 128)
        atomicAdd(&cnt[ebuf[i] >> 17], 1);
    __syncthreads();
    int mine = cnt[t];
    loff[t] = mine;
    __syncthreads();
    for (int off = 1; off < 128; off <<= 1) {
        int val = (t >= off) ? loff[t - off] : 0;
        __syncthreads();
        loff[t] += val;
        __syncthreads();
    }
    int excl = loff[t] - mine;
    int v = vbase + t;
    if (v < n) {
        rowptr[v] = lo + excl;
        degi[v] = mine;
        float d = (float)mine + 1.0f;
        dinv[v] = rsqrtf(d);
        sdeg[v] = sqrtf(d);
    }
    lcur[t] = lo + excl;
    __syncthreads();
    for (int i = lo + t; i < hi; i += 128) {
        unsigned int r = ebuf[i];
        int pos = atomicAdd(&lcur[r >> 17], 1);
        srcids[pos] = (int)(r & 0x1FFFFu);
    }
}

// ---- degree histogram (LDS-privatized) ----
__global__ void dhist_kernel(const int* __restrict__ degi, int* __restrict__ dh, int n) {
    __shared__ int lh[256];
    lh[threadIdx.x] = 0;
    __syncthreads();
    for (int v = blockIdx.x * blockDim.x + threadIdx.x; v < n; v += gridDim.x * blockDim.x)
        atomicAdd(&lh[min(degi[v], 255)], 1);
    __syncthreads();
    int c = lh[threadIdx.x];
    if (c) atomicAdd(&dh[threadIdx.x], c);
}

__global__ void dscan_kernel(const int* __restrict__ dh, int* __restrict__ dcur) {
    __shared__ int s[256];
    int t = threadIdx.x;
    int mine = dh[t];
    s[t] = mine;
    __syncthreads();
    for (int off = 1; off < 256; off <<= 1) {
        int val = (t >= off) ? s[t - off] : 0;
        __syncthreads();
        s[t] += val;
        __syncthreads();
    }
    dcur[t] = s[t] - mine;  // exclusive
}

// ---- placement: per-block chunk, LDS hist -> bulk range reservation -> LDS rank ----
__global__ void place_kernel(const int* __restrict__ degi, int* __restrict__ dcur,
                             int* __restrict__ perm, int n) {
    __shared__ int lh[256], lb[256];
    int chunk = (n + gridDim.x - 1) / gridDim.x;
    int beg = blockIdx.x * chunk;
    int end = min(beg + chunk, n);
    lh[threadIdx.x] = 0;
    __syncthreads();
    for (int v = beg + threadIdx.x; v < end; v += blockDim.x)
        atomicAdd(&lh[min(degi[v], 255)], 1);
    __syncthreads();
    int c = lh[threadIdx.x];
    lb[threadIdx.x] = c ? atomicAdd(&dcur[threadIdx.x], c) : 0;
    __syncthreads();
    lh[threadIdx.x] = 0;
    __syncthreads();
    for (int v = beg + threadIdx.x; v < end; v += blockDim.x) {
        int bin = min(degi[v], 255);
        int r = atomicAdd(&lh[bin], 1);
        perm[lb[bin] + r] = v;
    }
}

// ---- x0s = bf16(dinv[v] * x) ----
__global__ void cvt_kernel(const float* __restrict__ x, const float* __restrict__ dinv,
                           unsigned short* __restrict__ xb, int n4) {
    int i = blockIdx.x * blockDim.x + threadIdx.x;
    if (i < n4) {
        float dv = dinv[i >> 4];
        float4 f = ((const float4*)x)[i];
        ushort4 u;
        u.x = (unsigned short)f2bfu(f.x * dv);
        u.y = (unsigned short)f2bfu(f.y * dv);
        u.z = (unsigned short)f2bfu(f.z * dv);
        u.w = (unsigned short)f2bfu(f.w * dv);
        ((ushort4*)xb)[i] = u;
    }
}

// ---- stage W as MFMA A-fragments (W^T is the A operand), bf16 hi+lo split.
// frag f = t*2+kk (t: out-col 16-tile, kk: k 32-step); hi at [f], lo at [f+8].
// Lane l holds A[m = l&15][k = (l>>4)*8 + j], j=0..7 -> W[kk*32 + (l>>4)*8 + j][t*16 + (l&15)].
// LDS layout: wf[(f*64 + l)*8 + j] ushorts -> each lane reads one 16B short8.
__device__ __forceinline__ void stage_wfrag(const float* __restrict__ W,
                                            unsigned short* __restrict__ wf) {
    int l = threadIdx.x & 63;
    int m = l & 15;
    int kg = l >> 4;
    for (int f = threadIdx.x >> 6; f < 8; f += TPB / 64) {
        int t = f >> 1, kk = f & 1;
        int col = t * 16 + m;
        unsigned hw[4], lw[4];
#pragma unroll
        for (int j = 0; j < 4; ++j) {
            float w0 = W[(kk * 32 + kg * 8 + 2 * j) * 64 + col];
            float w1 = W[(kk * 32 + kg * 8 + 2 * j + 1) * 64 + col];
            unsigned x0 = __float_as_uint(w0), x1 = __float_as_uint(w1);
            hw[j] = (x0 >> 16) | (x1 & 0xffff0000u);          // truncated hi
            float r0 = w0 - __uint_as_float(x0 & 0xffff0000u);// exact residual
            float r1 = w1 - __uint_as_float(x1 & 0xffff0000u);
            lw[j] = f2bfu(r0) | (f2bfu(r1) << 16);
        }
        unsigned* dh = (unsigned*)(wf + ((size_t)(f * 64 + l) * 8));
        unsigned* dl = (unsigned*)(wf + ((size_t)((f + 8) * 64 + l) * 8));
#pragma unroll
        for (int j = 0; j < 4; ++j) { dh[j] = hw[j]; dl[j] = lw[j]; }
    }
}

// ---- build the B operand (t^T) fragment from an st row: 8 consecutive fp32,
// split into bf16 hi (truncated) + lo (RNE of exact residual).
__device__ __forceinline__ void build_bfrag(const float* __restrict__ tp,
                                            short8* bh, short8* bl) {
    float4 ta = *(const float4*)tp;
    float4 tb = *(const float4*)(tp + 4);
    float tv[8] = {ta.x, ta.y, ta.z, ta.w, tb.x, tb.y, tb.z, tb.w};
    union { short8 v; unsigned u[4]; } H, L;
#pragma unroll
    for (int j = 0; j < 4; ++j) {
        unsigned x0 = __float_as_uint(tv[2 * j]);
        unsigned x1 = __float_as_uint(tv[2 * j + 1]);
        H.u[j] = (x0 >> 16) | (x1 & 0xffff0000u);
        float r0 = tv[2 * j]     - __uint_as_float(x0 & 0xffff0000u);
        float r1 = tv[2 * j + 1] - __uint_as_float(x1 & 0xffff0000u);
        L.u[j] = f2bfu(r0) | (f2bfu(r1) << 16);
    }
    *bh = H.v;
    *bl = L.v;
}

// one out-col 16-tile: 6 MFMAs (bf16x3: hi*hi + lo*hi + hi*lo over 2 k-steps)
#define MMT(WFP, ACC, T) do { \
    short8 ah0 = (WFP)[((T) * 2    ) * 64 + lane]; \
    short8 al0 = (WFP)[((T) * 2 + 8) * 64 + lane]; \
    short8 ah1 = (WFP)[((T) * 2 + 1) * 64 + lane]; \
    short8 al1 = (WFP)[((T) * 2 + 9) * 64 + lane]; \
    ACC = MFMA16(ah0, bh0, ACC); \
    ACC = MFMA16(al0, bh0, ACC); \
    ACC = MFMA16(ah0, bl0, ACC); \
    ACC = MFMA16(ah1, bh1, ACC); \
    ACC = MFMA16(al1, bh1, ACC); \
    ACC = MFMA16(ah1, bl1, ACC); \
} while (0)

// ---- 4-slot gather, 8-edge-deep pipeline: lane = (slot s = lane>>4, quad g = lane&15).
// All 8 srcid loads then all 8 row loads issued before the fma tree -> 8 fetches
// in flight per lane. Uniform base + 32-bit offset for saddr-form loads.
struct GRes { float a0, a1, a2, a3; };
__device__ __forceinline__ GRes gather8s(const int* __restrict__ srcids, int beg, int deg,
                                         int md, const unsigned short* __restrict__ xsb,
                                         int ge) {
    GRes r{0.0f, 0.0f, 0.0f, 0.0f};
    for (int i = 0; i < md; i += 8) {
        int src[8];
#pragma unroll
        for (int u = 0; u < 8; ++u) {
            int e = i + u;
            src[u] = srcids[beg + ((e < deg) ? e : 0)];
        }
        int2 q[8];
#pragma unroll
        for (int u = 0; u < 8; ++u)
            q[u] = *(const int2*)(xsb + ((unsigned)src[u] * 64u + (unsigned)ge));
#pragma unroll
        for (int u = 0; u < 8; ++u) {
            float m = (i + u < deg) ? 1.0f : 0.0f;
            r.a0 = fmaf(m, lo16(q[u].x), r.a0);
            r.a1 = fmaf(m, hi16(q[u].x), r.a1);
            r.a2 = fmaf(m, lo16(q[u].y), r.a2);
            r.a3 = fmaf(m, hi16(q[u].y), r.a3);
        }
    }
    return r;
}

__device__ __forceinline__ void st_relu4(unsigned short* p, f32x4 a, float sc) {
    ushort4 u;
    u.x = (unsigned short)f2bfu(fmaxf(a[0], 0.f) * sc);
    u.y = (unsigned short)f2bfu(fmaxf(a[1], 0.f) * sc);
    u.z = (unsigned short)f2bfu(fmaxf(a[2], 0.f) * sc);
    u.w = (unsigned short)f2bfu(fmaxf(a[3], 0.f) * sc);
    *(ushort4*)p = u;
}

__device__ __forceinline__ void st_plain4(unsigned short* p, f32x4 a) {
    ushort4 u;
    u.x = (unsigned short)f2bfu(a[0]);
    u.y = (unsigned short)f2bfu(a[1]);
    u.z = (unsigned short)f2bfu(a[2]);
    u.w = (unsigned short)f2bfu(a[3]);
    *(ushort4*)p = u;
}

// ---- fused GCN2Conv layer: ys_out = dinv * relu( t @ W ),
//      t = 0.9*dinv*(S + xs_self) + 0.1*sdeg*xs_self; matmul on MFMA (bf16x3).
__global__ __launch_bounds__(256) void layer_kernel(
        const int* __restrict__ rowptr, const int* __restrict__ degi,
        const int* __restrict__ srcids, const int* __restrict__ perm,
        const unsigned short* __restrict__ xsb, const float* __restrict__ dinv,
        const float* __restrict__ sdeg, const float* __restrict__ W,
        unsigned short* __restrict__ yb, int n) {
    __shared__ __align__(16) float st[4][4][68];           // 68 stride: 16B-aligned, bank-spread
    __shared__ __align__(16) unsigned short wf[16 * 64 * 8];
    int wid = threadIdx.x >> 6;
    int lane = threadIdx.x & 63;
    int s = lane >> 4;    // gather: node slot   | matmul: k-group kg
    int g = lane & 15;    // gather: feature quad| matmul: node (B col)
    stage_wfrag(W, wf);
    __syncthreads();
    const short8* wfp = (const short8*)wf;
    int ntile = (n + 15) >> 4;
    // reversed: high-degree tiles (end of perm) start first -> no heavy tail
    for (int tile = ntile - 1 - blockIdx.x; tile >= 0; tile -= gridDim.x) {
        int base = tile * 16 + wid * 4;
        int vb = base + s;
        int vbc = (vb < n) ? vb : n - 1;
        int v = perm[vbc];
        int beg = rowptr[v];
        int deg = degi[v];
        int md = max(deg, __shfl_xor(deg, 16));
        md = max(md, __shfl_xor(md, 32));
        GRes r = gather8s(srcids, beg, deg, md, xsb, g * 4);
        int2 qs = *(const int2*)(xsb + ((unsigned)v * 64u + (unsigned)(g * 4)));
        float xs0 = lo16(qs.x), xs1 = hi16(qs.x), xs2 = lo16(qs.y), xs3 = hi16(qs.y);
        float c9 = 0.9f * dinv[v];
        float c1 = 0.1f * sdeg[v];
        float4 t4;
        t4.x = c9 * (r.a0 + xs0) + c1 * xs0;
        t4.y = c9 * (r.a1 + xs1) + c1 * xs1;
        t4.z = c9 * (r.a2 + xs2) + c1 * xs2;
        t4.w = c9 * (r.a3 + xs3) + c1 * xs3;
        *(float4*)&st[wid][s][g * 4] = t4;
        __builtin_amdgcn_wave_barrier();
        // ---- MFMA phase: D[outf][node] = W^T (A) x t^T (B) ----
        int vb2 = base + g;                       // node = g
        int v2c = perm[(vb2 < n) ? vb2 : n - 1];
        float dv2 = dinv[v2c];
        const float* strow = st[wid][g & 3];
        short8 bh0, bl0, bh1, bl1;
        build_bfrag(strow + s * 8,      &bh0, &bl0);
        build_bfrag(strow + 32 + s * 8, &bh1, &bl1);
        f32x4 ac0 = {0.f, 0.f, 0.f, 0.f}, ac1 = {0.f, 0.f, 0.f, 0.f};
        f32x4 ac2 = {0.f, 0.f, 0.f, 0.f}, ac3 = {0.f, 0.f, 0.f, 0.f};
        MMT(wfp, ac0, 0); MMT(wfp, ac1, 1); MMT(wfp, ac2, 2); MMT(wfp, ac3, 3);
        __builtin_amdgcn_wave_barrier();
        if (g < 4 && vb2 < n) {
            unsigned short* yp = yb + ((size_t)(unsigned)v2c << 6) + (s << 2);
            st_relu4(yp,      ac0, dv2);
            st_relu4(yp + 16, ac1, dv2);
            st_relu4(yp + 32, ac2, dv2);
            st_relu4(yp + 48, ac3, dv2);
        }
    }
}

// ---- last GCN2Conv layer fused with GCNConv GEMM: xw = (dinv*relu(t@W)) @ Wg ----
__global__ __launch_bounds__(256) void layer_fused_kernel(
        const int* __restrict__ rowptr, const int* __restrict__ degi,
        const int* __restrict__ srcids, const int* __restrict__ perm,
        const unsigned short* __restrict__ xsb, const float* __restrict__ dinv,
        const float* __restrict__ sdeg, const float* __restrict__ W,
        const float* __restrict__ Wg, unsigned short* __restrict__ yb, int n) {
    __shared__ __align__(16) float st[4][4][68];
    __shared__ __align__(16) unsigned short wf[16 * 64 * 8];
    __shared__ __align__(16) unsigned short wgf[16 * 64 * 8];
    int wid = threadIdx.x >> 6;
    int lane = threadIdx.x & 63;
    int s = lane >> 4;
    int g = lane & 15;
    stage_wfrag(W, wf);
    stage_wfrag(Wg, wgf);
    __syncthreads();
    const short8* wfp = (const short8*)wf;
    const short8* wgp = (const short8*)wgf;
    int ntile = (n + 15) >> 4;
    for (int tile = ntile - 1 - blockIdx.x; tile >= 0; tile -= gridDim.x) {
        int base = tile * 16 + wid * 4;
        int vb = base + s;
        int vbc = (vb < n) ? vb : n - 1;
        int v = perm[vbc];
        int beg = rowptr[v];
        int deg = degi[v];
        int md = max(deg, __shfl_xor(deg, 16));
        md = max(md, __shfl_xor(md, 32));
        GRes r = gather8s(srcids, beg, deg, md, xsb, g * 4);
        int2 qs = *(const int2*)(xsb + ((unsigned)v * 64u + (unsigned)(g * 4)));
        float xs0 = lo16(qs.x), xs1 = hi16(qs.x), xs2 = lo16(qs.y), xs3 = hi16(qs.y);
        float c9 = 0.9f * dinv[v];
        float c1 = 0.1f * sdeg[v];
        float4 t4;
        t4.x = c9 * (r.a0 + xs0) + c1 * xs0;
        t4.y = c9 * (r.a1 + xs1) + c1 * xs1;
        t4.z = c9 * (r.a2 + xs2) + c1 * xs2;
        t4.w = c9 * (r.a3 + xs3) + c1 * xs3;
        *(float4*)&st[wid][s][g * 4] = t4;
        __builtin_amdgcn_wave_barrier();
        // ---- matmul 1: y3s = dinv * relu(t @ W) ----
        int vb2 = base + g;
        int v2c = perm[(vb2 < n) ? vb2 : n - 1];
        float dv2 = dinv[v2c];
        const float* strow = st[wid][g & 3];
        {
            short8 bh0, bl0, bh1, bl1;
            build_bfrag(strow + s * 8,      &bh0, &bl0);
            build_bfrag(strow + 32 + s * 8, &bh1, &bl1);
            f32x4 ac0 = {0.f, 0.f, 0.f, 0.f}, ac1 = {0.f, 0.f, 0.f, 0.f};
            f32x4 ac2 = {0.f, 0.f, 0.f, 0.f}, ac3 = {0.f, 0.f, 0.f, 0.f};
            MMT(wfp, ac0, 0); MMT(wfp, ac1, 1); MMT(wfp, ac2, 2); MMT(wfp, ac3, 3);
            __builtin_amdgcn_wave_barrier();   // all B reads of matmul1 done (DS in-order)
            if (g < 4) {                        // write y3s back to st (fp32, full precision)
                float* sr = st[wid][g];
                *(float4*)(sr + (s << 2)) = make_float4(
                    fmaxf(ac0[0], 0.f) * dv2, fmaxf(ac0[1], 0.f) * dv2,
                    fmaxf(ac0[2], 0.f) * dv2, fmaxf(ac0[3], 0.f) * dv2);
                *(float4*)(sr + 16 + (s << 2)) = make_float4(
                    fmaxf(ac1[0], 0.f) * dv2, fmaxf(ac1[1], 0.f) * dv2,
                    fmaxf(ac1[2], 0.f) * dv2, fmaxf(ac1[3], 0.f) * dv2);
                *(float4*)(sr + 32 + (s << 2)) = make_float4(
                    fmaxf(ac2[0], 0.f) * dv2, fmaxf(ac2[1], 0.f) * dv2,
                    fmaxf(ac2[2], 0.f) * dv2, fmaxf(ac2[3], 0.f) * dv2);
                *(float4*)(sr + 48 + (s << 2)) = make_float4(
                    fmaxf(ac3[0], 0.f) * dv2, fmaxf(ac3[1], 0.f) * dv2,
                    fmaxf(ac3[2], 0.f) * dv2, fmaxf(ac3[3], 0.f) * dv2);
            }
        }
        __builtin_amdgcn_wave_barrier();
        // ---- matmul 2: xw = y3s @ Wg (no relu, no extra scale) ----
        {
            short8 bh0, bl0, bh1, bl1;
            build_bfrag(strow + s * 8,      &bh0, &bl0);
            build_bfrag(strow + 32 + s * 8, &bh1, &bl1);
            f32x4 ac0 = {0.f, 0.f, 0.f, 0.f}, ac1 = {0.f, 0.f, 0.f, 0.f};
            f32x4 ac2 = {0.f, 0.f, 0.f, 0.f}, ac3 = {0.f, 0.f, 0.f, 0.f};
            MMT(wgp, ac0, 0); MMT(wgp, ac1, 1); MMT(wgp, ac2, 2); MMT(wgp, ac3, 3);
            __builtin_amdgcn_wave_barrier();
            if (g < 4 && vb2 < n) {
                unsigned short* yp = yb + ((size_t)(unsigned)v2c << 6) + (s << 2);
                st_plain4(yp,      ac0);
                st_plain4(yp + 16, ac1);
                st_plain4(yp + 32, ac2);
                st_plain4(yp + 48, ac3);
            }
        }
    }
}

// ---- final: h = dinv*(S + xws_self) + b_gcn; out1 = h@W1+b1; out2 = h@W2+b2 ----
__global__ __launch_bounds__(256) void heads_kernel(
        const int* __restrict__ rowptr, const int* __restrict__ degi,
        const int* __restrict__ srcids, const int* __restrict__ perm,
        const unsigned short* __restrict__ xwb, const float* __restrict__ dinv,
        const float* __restrict__ bg,
        const float* __restrict__ W1, const float* __restrict__ b1,
        const float* __restrict__ W2, const float* __restrict__ b2,
        float* __restrict__ out, int n) {
    __shared__ __align__(16) float hs[4][4][64];
    __shared__ __align__(16) float whd[448];   // whd[j*64+k], j=0..6
    __shared__ float bs[8];
    int wid = threadIdx.x >> 6;
    int lane = threadIdx.x & 63;
    int s = lane >> 4;
    int g = lane & 15;
    for (int i = threadIdx.x; i < 448; i += TPB) {   // blockDim 256 < 448: loop!
        int j = i >> 6, k = i & 63;
        whd[i] = (j < 4) ? W1[k * 4 + j] : W2[k * 3 + (j - 4)];
    }
    if (threadIdx.x < 7) bs[threadIdx.x] = (threadIdx.x < 4) ? b1[threadIdx.x] : b2[threadIdx.x - 4];
    __syncthreads();
    int j = lane >> 3;
    int k0 = (lane & 7) * 8;
    int ntile = (n + 15) >> 4;
    for (int tile = ntile - 1 - blockIdx.x; tile >= 0; tile -= gridDim.x) {
        int base = tile * 16 + wid * 4;
        int vb = base + s;
        int vbc = (vb < n) ? vb : n - 1;
        int v = perm[vbc];
        int beg = rowptr[v];
        int deg = degi[v];
        int md = max(deg, __shfl_xor(deg, 16));
        md = max(md, __shfl_xor(md, 32));
        GRes r = gather8s(srcids, beg, deg, md, xwb, g * 4);
        int2 qs = *(const int2*)(xwb + ((unsigned)v * 64u + (unsigned)(g * 4)));
        float dv = dinv[v];
        float4 bq = *(const float4*)(bg + g * 4);
        float4 h4;
        h4.x = dv * (r.a0 + lo16(qs.x)) + bq.x;
        h4.y = dv * (r.a1 + hi16(qs.x)) + bq.y;
        h4.z = dv * (r.a2 + lo16(qs.y)) + bq.z;
        h4.w = dv * (r.a3 + hi16(qs.y)) + bq.w;
        if (vb < n)
            *(float4*)&out[(size_t)7 * n + (size_t)(unsigned)v * 64 + g * 4] = h4;
        *(float4*)&hs[wid][s][g * 4] = h4;
        __builtin_amdgcn_wave_barrier();
#pragma unroll
        for (int ss = 0; ss < 4; ++ss) {
            int vb2 = base + ss;
            if (vb2 >= n) break;
            int v2 = perm[vb2];
            float part = 0.0f;
            if (j < 7) {
                float4 h0 = *(const float4*)&hs[wid][ss][k0];
                float4 h1 = *(const float4*)&hs[wid][ss][k0 + 4];
                const float4* wq = (const float4*)&whd[j * 64 + k0];
                float4 w0 = wq[0], w1 = wq[1];
                part = h0.x * w0.x + h0.y * w0.y + h0.z * w0.z + h0.w * w0.w
                     + h1.x * w1.x + h1.y * w1.y + h1.z * w1.z + h1.w * w1.w;
            }
            part += __shfl_down(part, 4);
            part += __shfl_down(part, 2);
            part += __shfl_down(part, 1);
            if ((lane & 7) == 0 && j < 7) {
                float sv = bs[j] + part;
                if (j < 4) out[(size_t)v2 * 4 + j] = sv;
                else       out[(size_t)4 * n + (size_t)v2 * 3 + (j - 4)] = sv;
            }
        }
        __builtin_amdgcn_wave_barrier();
    }
}

extern "C" void kernel_launch(void* const* d_in, const int* in_sizes, int n_in,
                              void* d_out, int out_size, void* d_ws, size_t ws_size,
                              hipStream_t stream) {
    const float* x     = (const float*)d_in[0];
    const int*   ei    = (const int*)d_in[1];
    const float* Ws    = (const float*)d_in[2];
    const float* W_gcn = (const float*)d_in[3];
    const float* b_gcn = (const float*)d_in[4];
    const float* W1    = (const float*)d_in[5];
    const float* b1    = (const float*)d_in[6];
    const float* W2    = (const float*)d_in[7];
    const float* b2    = (const float*)d_in[8];
    float* out = (float*)d_out;

    const int N = in_sizes[0] / 64;
    const int E = in_sizes[1] / 2;
    const int NLAYERS = in_sizes[2] / 4096;  // L-1 = 3
    const int B = (N + 127) >> NBSH;         // node buckets of 128

    // ws layout (ints): degi[N] rowptr[N] bh[800] bcur[800] boff[800]
    //                   dh[256] dcur[256] perm[N] srcids[E+64] ebuf[E]
    // (floats): dinv[N] sdeg[N] | (ushort): x0s, bufA, bufB (N*64 each)
    int*   degi   = (int*)d_ws;
    int*   rowptr = degi + N;
    int*   bh     = rowptr + N;
    int*   bcur   = bh + 800;
    int*   boff   = bcur + 800;
    int*   dh     = boff + 800;
    int*   dcur   = dh + 256;
    int*   perm   = dcur + 256;
    int*   srcids = perm + N;
    unsigned int* ebuf = (unsigned int*)(srcids + E + 64);
    float* dinv   = (float*)(ebuf + E);
    float* sdeg   = dinv + N;
    unsigned short* x0s  = (unsigned short*)(sdeg + N);
    unsigned short* bufA = x0s + (size_t)N * 64;
    unsigned short* bufB = bufA + (size_t)N * 64;

    const int WGRID = 4096;

    // ---- CSR build: two-pass bucket sort ----
    hipMemsetAsync(bh, 0, 800 * sizeof(int), stream);
    hipMemsetAsync(dh, 0, 256 * sizeof(int), stream);
    hipMemsetAsync(srcids + E, 0, 64 * sizeof(int), stream);  // gather tail pad
    ebhist_kernel<<<120, TPB, 0, stream>>>(ei + E, bh, E, B);
    bscan_kernel<<<1, 256, 0, stream>>>(bh, bcur, boff, B, E);
    bucket_scatter_kernel<<<120, TPB, 0, stream>>>(ei, bcur, ebuf, E, B);
    bucket_place_kernel<<<B, 128, 0, stream>>>(boff, ebuf, rowptr, degi, dinv, sdeg,
                                               srcids, N);
    // ---- degree-sorted permutation ----
    dhist_kernel<<<64, 256, 0, stream>>>(degi, dh, N);
    dscan_kernel<<<1, 256, 0, stream>>>(dh, dcur);
    place_kernel<<<64, 256, 0, stream>>>(degi, dcur, perm, N);
    cvt_kernel<<<(N * 16 + TPB - 1) / TPB, TPB, 0, stream>>>(x, dinv, x0s, N * 16);

    // ---- GCN2Conv layers: first NLAYERS-1 plain, last fused with GCNConv GEMM ----
    const unsigned short* xcur = x0s;
    unsigned short* ybuf = bufA;
    for (int i = 0; i < NLAYERS - 1; ++i) {
        layer_kernel<<<WGRID, TPB, 0, stream>>>(rowptr, degi, srcids, perm, xcur,
                                                dinv, sdeg, Ws + (size_t)i * 4096, ybuf, N);
        xcur = ybuf;
        ybuf = (ybuf == bufA) ? bufB : bufA;
    }
    layer_fused_kernel<<<WGRID, TPB, 0, stream>>>(rowptr, degi, srcids, perm, xcur,
                                                  dinv, sdeg,
                                                  Ws + (size_t)(NLAYERS - 1) * 4096,
                                                  W_gcn, ybuf, N);
    unsigned short* xw = ybuf;

    // ---- heads ----
    heads_kernel<<<WGRID, TPB, 0, stream>>>(rowptr, degi, srcids, perm, xw, dinv,
                                            b_gcn, W1, b1, W2, b2, out, N);
}

// Round 2
// 311.049 us; speedup vs baseline: 1.3082x; 1.0009x over previous
//
#include <hip/hip_runtime.h>
#include <hip/hip_bf16.h>

// GCNII fused, bf16 pre-scaled activations (xs = dinv*x), src-only CSR built by
// two-pass bucket sort, 4-node-slot gather waves with 8-edge-deep load pipelining,
// degree-sorted node permutation. N=100000, E=1000000, F=64.
// This version: block-cooperative 16-node MFMA tile (wave w computes outf
// [16w,16w+16) for all 16 nodes -> 6 MFMAs/wave/tile instead of 24 with 3/4
// discarded), v_cvt_pk_bf16_f32 for all f32->bf16 splits/packs, clamp-free
// gather (over-reads masked, land in CSR pad), WGRID 2048 to amortize W staging.
// Output: concat(out1 [N*4], out2 [N*3], h [N*64]) fp32.
// NOTE: record packing (dst&127)<<17 | src requires N <= 131072.

#define TPB 256
#define NBSH 7    // 128 nodes per bucket
typedef __hip_bfloat16 bf16;
typedef __attribute__((ext_vector_type(8))) short short8;  // 8 bf16 = 4 VGPR
typedef __attribute__((ext_vector_type(4))) float f32x4;   // MFMA C/D frag

#define MFMA16(A, B, C) __builtin_amdgcn_mfma_f32_16x16x32_bf16((A), (B), (C), 0, 0, 0)

__device__ __forceinline__ float lo16(int u) { return __int_as_float(u << 16); }
__device__ __forceinline__ float hi16(int u) { return __int_as_float(u & 0xffff0000); }

// packed f32x2 -> bf16x2 (RNE), lo in [15:0], hi in [31:16]
__device__ __forceinline__ unsigned cvtpk(float lo, float hi) {
    unsigned r;
    asm("v_cvt_pk_bf16_f32 %0, %1, %2" : "=v"(r) : "v"(lo), "v"(hi));
    return r;
}

// ---- pass 0: bucket histogram (LDS-privatized) ----
__global__ void ebhist_kernel(const int* __restrict__ col, int* __restrict__ bh,
                              int E, int B) {
    __shared__ int lh[800];
    for (int i = threadIdx.x; i < B; i += blockDim.x) lh[i] = 0;
    __syncthreads();
    for (int e = blockIdx.x * blockDim.x + threadIdx.x; e < E; e += gridDim.x * blockDim.x)
        atomicAdd(&lh[col[e] >> NBSH], 1);
    __syncthreads();
    for (int i = threadIdx.x; i < B; i += blockDim.x) {
        int c = lh[i];
        if (c) atomicAdd(&bh[i], c);
    }
}

// ---- exclusive scan of bh -> bcur (cursors) and boff (bounds, boff[B]=E) ----
__global__ void bscan_kernel(const int* __restrict__ bh, int* __restrict__ bcur,
                             int* __restrict__ boff, int B, int E) {
    __shared__ int s[256];
    int t = threadIdx.x;
    int v[4]; int sum = 0;
#pragma unroll
    for (int i = 0; i < 4; ++i) {
        int idx = t * 4 + i;
        v[i] = (idx < B) ? bh[idx] : 0;
        sum += v[i];
    }
    s[t] = sum;
    __syncthreads();
    for (int off = 1; off < 256; off <<= 1) {
        int val = (t >= off) ? s[t - off] : 0;
        __syncthreads();
        s[t] += val;
        __syncthreads();
    }
    int run = s[t] - sum;
#pragma unroll
    for (int i = 0; i < 4; ++i) {
        int idx = t * 4 + i;
        if (idx < B) { bcur[idx] = run; boff[idx] = run; }
        run += v[i];
    }
    if (t == 255) boff[B] = E;
}

// ---- pass 1: bucket scatter with per-block range reservation ----
__global__ void bucket_scatter_kernel(const int* __restrict__ ei, int* __restrict__ bcur,
                                      unsigned int* __restrict__ ebuf, int E, int B) {
    __shared__ int lh[800], lb[800];
    int chunk = (E + gridDim.x - 1) / gridDim.x;
    int beg = blockIdx.x * chunk;
    int end = min(beg + chunk, E);
    for (int i = threadIdx.x; i < B; i += blockDim.x) lh[i] = 0;
    __syncthreads();
    for (int e = beg + threadIdx.x; e < end; e += blockDim.x)
        atomicAdd(&lh[ei[E + e] >> NBSH], 1);
    __syncthreads();
    for (int i = threadIdx.x; i < B; i += blockDim.x) {
        int c = lh[i];
        lb[i] = c ? atomicAdd(&bcur[i], c) : 0;   // one global atomic per bin per block
    }
    __syncthreads();
    for (int i = threadIdx.x; i < B; i += blockDim.x) lh[i] = 0;
    __syncthreads();
    for (int e = beg + threadIdx.x; e < end; e += blockDim.x) {
        int r = ei[e];
        int c = ei[E + e];
        int bin = c >> NBSH;
        int rank = atomicAdd(&lh[bin], 1);        // LDS rank
        ebuf[lb[bin] + rank] = ((unsigned)(c & 127) << 17) | (unsigned)r;
    }
}

// ---- pass 2: per-bucket place; also emits degi/rowptr/dinv/sdeg ----
__global__ __launch_bounds__(128) void bucket_place_kernel(
        const int* __restrict__ boff, const unsigned int* __restrict__ ebuf,
        int* __restrict__ rowptr, int* __restrict__ degi,
        float* __restrict__ dinv, float* __restrict__ sdeg,
        int* __restrict__ srcids, int n) {
    __shared__ int cnt[128], loff[128], lcur[128];
    int b = blockIdx.x;
    int t = threadIdx.x;
    int lo = boff[b];
    int hi = boff[b + 1];
    int vbase = b << NBSH;
    cnt[t] = 0;
    __syncthreads();
    for (int i = lo + t; i < hi; i += 128)
        atomicAdd(&cnt[ebuf[i] >> 17], 1);
    __syncthreads();
    int mine = cnt[t];
    loff[t] = mine;
    __syncthreads();
    for (int off = 1; off < 128; off <<= 1) {
        int val = (t >= off) ? loff[t - off] : 0;
        __syncthreads();
        loff[t] += val;
        __syncthreads();
    }
    int excl = loff[t] - mine;
    int v = vbase + t;
    if (v < n) {
        rowptr[v] = lo + excl;
        degi[v] = mine;
        float d = (float)mine + 1.0f;
        dinv[v] = rsqrtf(d);
        sdeg[v] = sqrtf(d);
    }
    lcur[t] = lo + excl;
    __syncthreads();
    for (int i = lo + t; i < hi; i += 128) {
        unsigned int r = ebuf[i];
        int pos = atomicAdd(&lcur[r >> 17], 1);
        srcids[pos] = (int)(r & 0x1FFFFu);
    }
}

// ---- degree histogram (LDS-privatized) ----
__global__ void dhist_kernel(const int* __restrict__ degi, int* __restrict__ dh, int n) {
    __shared__ int lh[256];
    lh[threadIdx.x] = 0;
    __syncthreads();
    for (int v = blockIdx.x * blockDim.x + threadIdx.x; v < n; v += gridDim.x * blockDim.x)
        atomicAdd(&lh[min(degi[v], 255)], 1);
    __syncthreads();
    int c = lh[threadIdx.x];
    if (c) atomicAdd(&dh[threadIdx.x], c);
}

__global__ void dscan_kernel(const int* __restrict__ dh, int* __restrict__ dcur) {
    __shared__ int s[256];
    int t = threadIdx.x;
    int mine = dh[t];
    s[t] = mine;
    __syncthreads();
    for (int off = 1; off < 256; off <<= 1) {
        int val = (t >= off) ? s[t - off] : 0;
        __syncthreads();
        s[t] += val;
        __syncthreads();
    }
    dcur[t] = s[t] - mine;  // exclusive
}

// ---- placement: per-block chunk, LDS hist -> bulk range reservation -> LDS rank ----
__global__ void place_kernel(const int* __restrict__ degi, int* __restrict__ dcur,
                             int* __restrict__ perm, int n) {
    __shared__ int lh[256], lb[256];
    int chunk = (n + gridDim.x - 1) / gridDim.x;
    int beg = blockIdx.x * chunk;
    int end = min(beg + chunk, n);
    lh[threadIdx.x] = 0;
    __syncthreads();
    for (int v = beg + threadIdx.x; v < end; v += blockDim.x)
        atomicAdd(&lh[min(degi[v], 255)], 1);
    __syncthreads();
    int c = lh[threadIdx.x];
    lb[threadIdx.x] = c ? atomicAdd(&dcur[threadIdx.x], c) : 0;
    __syncthreads();
    lh[threadIdx.x] = 0;
    __syncthreads();
    for (int v = beg + threadIdx.x; v < end; v += blockDim.x) {
        int bin = min(degi[v], 255);
        int r = atomicAdd(&lh[bin], 1);
        perm[lb[bin] + r] = v;
    }
}

// ---- x0s = bf16(dinv[v] * x) ----
__global__ void cvt_kernel(const float* __restrict__ x, const float* __restrict__ dinv,
                           unsigned short* __restrict__ xb, int n4) {
    int i = blockIdx.x * blockDim.x + threadIdx.x;
    if (i < n4) {
        float dv = dinv[i >> 4];
        float4 f = ((const float4*)x)[i];
        uint2 o;
        o.x = cvtpk(f.x * dv, f.y * dv);
        o.y = cvtpk(f.z * dv, f.w * dv);
        ((uint2*)xb)[i] = o;
    }
}

// ---- stage W as MFMA A-fragments (W^T is the A operand), bf16 hi+lo split (RNE).
// frag f = t*2+kk (t: out-col 16-tile, kk: k 32-step); hi at [f], lo at [f+8].
// Lane l holds A[m = l&15][k = (l>>4)*8 + j], j=0..7 -> W[kk*32 + (l>>4)*8 + j][t*16 + (l&15)].
// LDS layout: wf[(f*64 + l)*8 + j] ushorts -> each lane reads one 16B short8.
__device__ __forceinline__ void stage_wfrag(const float* __restrict__ W,
                                            unsigned short* __restrict__ wf) {
    int l = threadIdx.x & 63;
    int m = l & 15;
    int kg = l >> 4;
    for (int f = threadIdx.x >> 6; f < 8; f += TPB / 64) {
        int t = f >> 1, kk = f & 1;
        int col = t * 16 + m;
        unsigned hw[4], lw[4];
#pragma unroll
        for (int j = 0; j < 4; ++j) {
            float w0 = W[(kk * 32 + kg * 8 + 2 * j) * 64 + col];
            float w1 = W[(kk * 32 + kg * 8 + 2 * j + 1) * 64 + col];
            unsigned h = cvtpk(w0, w1);
            float h0 = __uint_as_float(h << 16);
            float h1 = __uint_as_float(h & 0xffff0000u);
            hw[j] = h;
            lw[j] = cvtpk(w0 - h0, w1 - h1);   // residual exact -> RNE to bf16
        }
        unsigned* dh = (unsigned*)(wf + ((size_t)(f * 64 + l) * 8));
        unsigned* dl = (unsigned*)(wf + ((size_t)((f + 8) * 64 + l) * 8));
#pragma unroll
        for (int j = 0; j < 4; ++j) { dh[j] = hw[j]; dl[j] = lw[j]; }
    }
}

// ---- build the B operand (t^T) fragment from an st row: 8 consecutive fp32,
// split into bf16 hi (RNE) + lo (RNE of exact residual) via v_cvt_pk_bf16_f32.
__device__ __forceinline__ void build_bfrag(const float* __restrict__ tp,
                                            short8* bh, short8* bl) {
    float4 ta = *(const float4*)tp;
    float4 tb = *(const float4*)(tp + 4);
    float tv[8] = {ta.x, ta.y, ta.z, ta.w, tb.x, tb.y, tb.z, tb.w};
    union { short8 v; unsigned u[4]; } H, L;
#pragma unroll
    for (int j = 0; j < 4; ++j) {
        unsigned h = cvtpk(tv[2 * j], tv[2 * j + 1]);
        float h0 = __uint_as_float(h << 16);
        float h1 = __uint_as_float(h & 0xffff0000u);
        H.u[j] = h;
        L.u[j] = cvtpk(tv[2 * j] - h0, tv[2 * j + 1] - h1);
    }
    *bh = H.v;
    *bl = L.v;
}

// ---- 4-slot gather, 8-edge-deep pipeline: lane = (slot s = lane>>4, quad g = lane&15).
// All 8 srcid loads then all 8 row loads issued before the fma tree -> 8 fetches
// in flight per lane. No per-edge clamp: over-reads land in later CSR rows or the
// zeroed 64-entry pad and are masked out of the accumulation.
struct GRes { float a0, a1, a2, a3; };
__device__ __forceinline__ GRes gather8s(const int* __restrict__ srcids, int beg, int deg,
                                         int md, const unsigned short* __restrict__ xsb,
                                         int ge) {
    GRes r{0.0f, 0.0f, 0.0f, 0.0f};
    for (int i = 0; i < md; i += 8) {
        int src[8];
#pragma unroll
        for (int u = 0; u < 8; ++u)
            src[u] = srcids[beg + i + u];
        int2 q[8];
#pragma unroll
        for (int u = 0; u < 8; ++u)
            q[u] = *(const int2*)(xsb + ((unsigned)src[u] * 64u + (unsigned)ge));
#pragma unroll
        for (int u = 0; u < 8; ++u) {
            float m = (i + u < deg) ? 1.0f : 0.0f;
            r.a0 = fmaf(m, lo16(q[u].x), r.a0);
            r.a1 = fmaf(m, hi16(q[u].x), r.a1);
            r.a2 = fmaf(m, lo16(q[u].y), r.a2);
            r.a3 = fmaf(m, hi16(q[u].y), r.a3);
        }
    }
    return r;
}

__device__ __forceinline__ void st_relu4(unsigned short* p, f32x4 a, float sc) {
    uint2 o;
    o.x = cvtpk(fmaxf(a[0], 0.f) * sc, fmaxf(a[1], 0.f) * sc);
    o.y = cvtpk(fmaxf(a[2], 0.f) * sc, fmaxf(a[3], 0.f) * sc);
    *(uint2*)p = o;
}

__device__ __forceinline__ void st_plain4(unsigned short* p, f32x4 a) {
    uint2 o;
    o.x = cvtpk(a[0], a[1]);
    o.y = cvtpk(a[2], a[3]);
    *(uint2*)p = o;
}

// ---- fused GCN2Conv layer: ys_out = dinv * relu( t @ W ),
//      t = 0.9*dinv*(S + xs_self) + 0.1*sdeg*xs_self; block-coop MFMA (bf16x3).
// Wave wid computes outf [wid*16, wid*16+16) for all 16 nodes of the block tile.
__global__ __launch_bounds__(256) void layer_kernel(
        const int* __restrict__ rowptr, const int* __restrict__ degi,
        const int* __restrict__ srcids, const int* __restrict__ perm,
        const unsigned short* __restrict__ xsb, const float* __restrict__ dinv,
        const float* __restrict__ sdeg, const float* __restrict__ W,
        unsigned short* __restrict__ yb, int n) {
    __shared__ __align__(16) float st[16][68];             // 16 nodes x 64 feat (+4 pad)
    __shared__ __align__(16) unsigned short wf[16 * 64 * 8];
    int wid = threadIdx.x >> 6;
    int lane = threadIdx.x & 63;
    int s = lane >> 4;    // gather: node slot   | matmul: k-group
    int g = lane & 15;    // gather: feature quad| matmul: node (B col / D col)
    stage_wfrag(W, wf);
    __syncthreads();
    const short8* wfp = (const short8*)wf;
    int ntile = (n + 15) >> 4;
    // reversed: high-degree tiles (end of perm) start first -> no heavy tail
    for (int tile = ntile - 1 - blockIdx.x; tile >= 0; tile -= gridDim.x) {
        int base = tile * 16;
        int vb = base + wid * 4 + s;
        int vbc = (vb < n) ? vb : n - 1;
        int v = perm[vbc];
        int beg = rowptr[v];
        int deg = degi[v];
        int md = max(deg, __shfl_xor(deg, 16));
        md = max(md, __shfl_xor(md, 32));
        GRes r = gather8s(srcids, beg, deg, md, xsb, g * 4);
        int2 qs = *(const int2*)(xsb + ((unsigned)v * 64u + (unsigned)(g * 4)));
        float xs0 = lo16(qs.x), xs1 = hi16(qs.x), xs2 = lo16(qs.y), xs3 = hi16(qs.y);
        float c9 = 0.9f * dinv[v];
        float c1 = 0.1f * sdeg[v];
        float4 t4;
        t4.x = c9 * (r.a0 + xs0) + c1 * xs0;
        t4.y = c9 * (r.a1 + xs1) + c1 * xs1;
        t4.z = c9 * (r.a2 + xs2) + c1 * xs2;
        t4.w = c9 * (r.a3 + xs3) + c1 * xs3;
        *(float4*)&st[wid * 4 + s][g * 4] = t4;
        __syncthreads();                                   // st tile complete
        // ---- MFMA: D[outf = wid*16 + s*4 + j][node = g] ----
        int vb2 = base + g;
        int v2c = perm[(vb2 < n) ? vb2 : n - 1];
        float dv2 = dinv[v2c];
        const float* strow = st[g];
        short8 bh0, bl0, bh1, bl1;
        build_bfrag(strow + s * 8,      &bh0, &bl0);
        build_bfrag(strow + 32 + s * 8, &bh1, &bl1);
        __syncthreads();                                   // st reads done (reuse next tile)
        short8 ah0 = wfp[(wid * 2    ) * 64 + lane];
        short8 al0 = wfp[(wid * 2 + 8) * 64 + lane];
        short8 ah1 = wfp[(wid * 2 + 1) * 64 + lane];
        short8 al1 = wfp[(wid * 2 + 9) * 64 + lane];
        f32x4 ac = {0.f, 0.f, 0.f, 0.f};
        ac = MFMA16(ah0, bh0, ac);
        ac = MFMA16(al0, bh0, ac);
        ac = MFMA16(ah0, bl0, ac);
        ac = MFMA16(ah1, bh1, ac);
        ac = MFMA16(al1, bh1, ac);
        ac = MFMA16(ah1, bl1, ac);
        if (vb2 < n) {
            unsigned short* yp = yb + ((size_t)(unsigned)v2c << 6)
                               + (unsigned)(wid * 16 + s * 4);
            st_relu4(yp, ac, dv2);
        }
    }
}

// ---- last GCN2Conv layer fused with GCNConv GEMM: xw = (dinv*relu(t@W)) @ Wg ----
__global__ __launch_bounds__(256) void layer_fused_kernel(
        const int* __restrict__ rowptr, const int* __restrict__ degi,
        const int* __restrict__ srcids, const int* __restrict__ perm,
        const unsigned short* __restrict__ xsb, const float* __restrict__ dinv,
        const float* __restrict__ sdeg, const float* __restrict__ W,
        const float* __restrict__ Wg, unsigned short* __restrict__ yb, int n) {
    __shared__ __align__(16) float st[16][68];
    __shared__ __align__(16) unsigned short wf[16 * 64 * 8];
    __shared__ __align__(16) unsigned short wgf[16 * 64 * 8];
    int wid = threadIdx.x >> 6;
    int lane = threadIdx.x & 63;
    int s = lane >> 4;
    int g = lane & 15;
    stage_wfrag(W, wf);
    stage_wfrag(Wg, wgf);
    __syncthreads();
    const short8* wfp = (const short8*)wf;
    const short8* wgp = (const short8*)wgf;
    int ntile = (n + 15) >> 4;
    for (int tile = ntile - 1 - blockIdx.x; tile >= 0; tile -= gridDim.x) {
        int base = tile * 16;
        int vb = base + wid * 4 + s;
        int vbc = (vb < n) ? vb : n - 1;
        int v = perm[vbc];
        int beg = rowptr[v];
        int deg = degi[v];
        int md = max(deg, __shfl_xor(deg, 16));
        md = max(md, __shfl_xor(md, 32));
        GRes r = gather8s(srcids, beg, deg, md, xsb, g * 4);
        int2 qs = *(const int2*)(xsb + ((unsigned)v * 64u + (unsigned)(g * 4)));
        float xs0 = lo16(qs.x), xs1 = hi16(qs.x), xs2 = lo16(qs.y), xs3 = hi16(qs.y);
        float c9 = 0.9f * dinv[v];
        float c1 = 0.1f * sdeg[v];
        float4 t4;
        t4.x = c9 * (r.a0 + xs0) + c1 * xs0;
        t4.y = c9 * (r.a1 + xs1) + c1 * xs1;
        t4.z = c9 * (r.a2 + xs2) + c1 * xs2;
        t4.w = c9 * (r.a3 + xs3) + c1 * xs3;
        *(float4*)&st[wid * 4 + s][g * 4] = t4;
        __syncthreads();                                   // (A) st tile complete
        int vb2 = base + g;
        int v2c = perm[(vb2 < n) ? vb2 : n - 1];
        float dv2 = dinv[v2c];
        const float* strow = st[g];
        // ---- matmul 1: y3s = dinv * relu(t @ W), written back to st (fp32) ----
        {
            short8 bh0, bl0, bh1, bl1;
            build_bfrag(strow + s * 8,      &bh0, &bl0);
            build_bfrag(strow + 32 + s * 8, &bh1, &bl1);
            __syncthreads();                               // (B) all B1 reads done
            short8 ah0 = wfp[(wid * 2    ) * 64 + lane];
            short8 al0 = wfp[(wid * 2 + 8) * 64 + lane];
            short8 ah1 = wfp[(wid * 2 + 1) * 64 + lane];
            short8 al1 = wfp[(wid * 2 + 9) * 64 + lane];
            f32x4 ac = {0.f, 0.f, 0.f, 0.f};
            ac = MFMA16(ah0, bh0, ac);
            ac = MFMA16(al0, bh0, ac);
            ac = MFMA16(ah0, bl0, ac);
            ac = MFMA16(ah1, bh1, ac);
            ac = MFMA16(al1, bh1, ac);
            ac = MFMA16(ah1, bl1, ac);
            *(float4*)&st[g][wid * 16 + s * 4] = make_float4(
                fmaxf(ac[0], 0.f) * dv2, fmaxf(ac[1], 0.f) * dv2,
                fmaxf(ac[2], 0.f) * dv2, fmaxf(ac[3], 0.f) * dv2);
        }
        __syncthreads();                                   // (C) y3s writeback complete
        // ---- matmul 2: xw = y3s @ Wg (no relu, no extra scale) ----
        {
            short8 bh0, bl0, bh1, bl1;
            build_bfrag(strow + s * 8,      &bh0, &bl0);
            build_bfrag(strow + 32 + s * 8, &bh1, &bl1);
            short8 ah0 = wgp[(wid * 2    ) * 64 + lane];
            short8 al0 = wgp[(wid * 2 + 8) * 64 + lane];
            short8 ah1 = wgp[(wid * 2 + 1) * 64 + lane];
            short8 al1 = wgp[(wid * 2 + 9) * 64 + lane];
            f32x4 ac = {0.f, 0.f, 0.f, 0.f};
            ac = MFMA16(ah0, bh0, ac);
            ac = MFMA16(al0, bh0, ac);
            ac = MFMA16(ah0, bl0, ac);
            ac = MFMA16(ah1, bh1, ac);
            ac = MFMA16(al1, bh1, ac);
            ac = MFMA16(ah1, bl1, ac);
            __syncthreads();                               // (D) B2 reads done
            if (vb2 < n) {
                unsigned short* yp = yb + ((size_t)(unsigned)v2c << 6)
                                   + (unsigned)(wid * 16 + s * 4);
                st_plain4(yp, ac);
            }
        }
    }
}

// ---- final: h = dinv*(S + xws_self) + b_gcn; out1 = h@W1+b1; out2 = h@W2+b2 ----
__global__ __launch_bounds__(256) void heads_kernel(
        const int* __restrict__ rowptr, const int* __restrict__ degi,
        const int* __restrict__ srcids, const int* __restrict__ perm,
        const unsigned short* __restrict__ xwb, const float* __restrict__ dinv,
        const float* __restrict__ bg,
        const float* __restrict__ W1, const float* __restrict__ b1,
        const float* __restrict__ W2, const float* __restrict__ b2,
        float* __restrict__ out, int n) {
    __shared__ __align__(16) float hs[4][4][64];
    __shared__ __align__(16) float whd[448];   // whd[j*64+k], j=0..6
    __shared__ float bs[8];
    int wid = threadIdx.x >> 6;
    int lane = threadIdx.x & 63;
    int s = lane >> 4;
    int g = lane & 15;
    for (int i = threadIdx.x; i < 448; i += TPB) {   // blockDim 256 < 448: loop!
        int j = i >> 6, k = i & 63;
        whd[i] = (j < 4) ? W1[k * 4 + j] : W2[k * 3 + (j - 4)];
    }
    if (threadIdx.x < 7) bs[threadIdx.x] = (threadIdx.x < 4) ? b1[threadIdx.x] : b2[threadIdx.x - 4];
    __syncthreads();
    int j = lane >> 3;
    int k0 = (lane & 7) * 8;
    int ntile = (n + 15) >> 4;
    for (int tile = ntile - 1 - blockIdx.x; tile >= 0; tile -= gridDim.x) {
        int base = tile * 16 + wid * 4;
        int vb = base + s;
        int vbc = (vb < n) ? vb : n - 1;
        int v = perm[vbc];
        int beg = rowptr[v];
        int deg = degi[v];
        int md = max(deg, __shfl_xor(deg, 16));
        md = max(md, __shfl_xor(md, 32));
        GRes r = gather8s(srcids, beg, deg, md, xwb, g * 4);
        int2 qs = *(const int2*)(xwb + ((unsigned)v * 64u + (unsigned)(g * 4)));
        float dv = dinv[v];
        float4 bq = *(const float4*)(bg + g * 4);
        float4 h4;
        h4.x = dv * (r.a0 + lo16(qs.x)) + bq.x;
        h4.y = dv * (r.a1 + hi16(qs.x)) + bq.y;
        h4.z = dv * (r.a2 + lo16(qs.y)) + bq.z;
        h4.w = dv * (r.a3 + hi16(qs.y)) + bq.w;
        if (vb < n)
            *(float4*)&out[(size_t)7 * n + (size_t)(unsigned)v * 64 + g * 4] = h4;
        *(float4*)&hs[wid][s][g * 4] = h4;
        __builtin_amdgcn_wave_barrier();
#pragma unroll
        for (int ss = 0; ss < 4; ++ss) {
            int vb2 = base + ss;
            if (vb2 >= n) break;
            int v2 = perm[vb2];
            float part = 0.0f;
            if (j < 7) {
                float4 h0 = *(const float4*)&hs[wid][ss][k0];
                float4 h1 = *(const float4*)&hs[wid][ss][k0 + 4];
                const float4* wq = (const float4*)&whd[j * 64 + k0];
                float4 w0 = wq[0], w1 = wq[1];
                part = h0.x * w0.x + h0.y * w0.y + h0.z * w0.z + h0.w * w0.w
                     + h1.x * w1.x + h1.y * w1.y + h1.z * w1.z + h1.w * w1.w;
            }
            part += __shfl_down(part, 4);
            part += __shfl_down(part, 2);
            part += __shfl_down(part, 1);
            if ((lane & 7) == 0 && j < 7) {
                float sv = bs[j] + part;
                if (j < 4) out[(size_t)v2 * 4 + j] = sv;
                else       out[(size_t)4 * n + (size_t)v2 * 3 + (j - 4)] = sv;
            }
        }
        __builtin_amdgcn_wave_barrier();
    }
}

extern "C" void kernel_launch(void* const* d_in, const int* in_sizes, int n_in,
                              void* d_out, int out_size, void* d_ws, size_t ws_size,
                              hipStream_t stream) {
    const float* x     = (const float*)d_in[0];
    const int*   ei    = (const int*)d_in[1];
    const float* Ws    = (const float*)d_in[2];
    const float* W_gcn = (const float*)d_in[3];
    const float* b_gcn = (const float*)d_in[4];
    const float* W1    = (const float*)d_in[5];
    const float* b1    = (const float*)d_in[6];
    const float* W2    = (const float*)d_in[7];
    const float* b2    = (const float*)d_in[8];
    float* out = (float*)d_out;

    const int N = in_sizes[0] / 64;
    const int E = in_sizes[1] / 2;
    const int NLAYERS = in_sizes[2] / 4096;  // L-1 = 3
    const int B = (N + 127) >> NBSH;         // node buckets of 128

    // ws layout (ints): degi[N] rowptr[N] bh[800] bcur[800] boff[800]
    //                   dh[256] dcur[256] perm[N] srcids[E+64] ebuf[E]
    // (floats): dinv[N] sdeg[N] | (ushort): x0s, bufA, bufB (N*64 each)
    int*   degi   = (int*)d_ws;
    int*   rowptr = degi + N;
    int*   bh     = rowptr + N;
    int*   bcur   = bh + 800;
    int*   boff   = bcur + 800;
    int*   dh     = boff + 800;
    int*   dcur   = dh + 256;
    int*   perm   = dcur + 256;
    int*   srcids = perm + N;
    unsigned int* ebuf = (unsigned int*)(srcids + E + 64);
    float* dinv   = (float*)(ebuf + E);
    float* sdeg   = dinv + N;
    unsigned short* x0s  = (unsigned short*)(sdeg + N);
    unsigned short* bufA = x0s + (size_t)N * 64;
    unsigned short* bufB = bufA + (size_t)N * 64;

    const int WGRID_L = 2048;   // ~3 tiles/block: amortize 16KB W staging
    const int WGRID_H = 4096;

    // ---- CSR build: two-pass bucket sort ----
    hipMemsetAsync(bh, 0, 800 * sizeof(int), stream);
    hipMemsetAsync(dh, 0, 256 * sizeof(int), stream);
    hipMemsetAsync(srcids + E, 0, 64 * sizeof(int), stream);  // gather tail pad
    ebhist_kernel<<<120, TPB, 0, stream>>>(ei + E, bh, E, B);
    bscan_kernel<<<1, 256, 0, stream>>>(bh, bcur, boff, B, E);
    bucket_scatter_kernel<<<120, TPB, 0, stream>>>(ei, bcur, ebuf, E, B);
    bucket_place_kernel<<<B, 128, 0, stream>>>(boff, ebuf, rowptr, degi, dinv, sdeg,
                                               srcids, N);
    // ---- degree-sorted permutation ----
    dhist_kernel<<<64, 256, 0, stream>>>(degi, dh, N);
    dscan_kernel<<<1, 256, 0, stream>>>(dh, dcur);
    place_kernel<<<64, 256, 0, stream>>>(degi, dcur, perm, N);
    cvt_kernel<<<(N * 16 + TPB - 1) / TPB, TPB, 0, stream>>>(x, dinv, x0s, N * 16);

    // ---- GCN2Conv layers: first NLAYERS-1 plain, last fused with GCNConv GEMM ----
    const unsigned short* xcur = x0s;
    unsigned short* ybuf = bufA;
    for (int i = 0; i < NLAYERS - 1; ++i) {
        layer_kernel<<<WGRID_L, TPB, 0, stream>>>(rowptr, degi, srcids, perm, xcur,
                                                  dinv, sdeg, Ws + (size_t)i * 4096, ybuf, N);
        xcur = ybuf;
        ybuf = (ybuf == bufA) ? bufB : bufA;
    }
    layer_fused_kernel<<<WGRID_L, TPB, 0, stream>>>(rowptr, degi, srcids, perm, xcur,
                                                    dinv, sdeg,
                                                    Ws + (size_t)(NLAYERS - 1) * 4096,
                                                    W_gcn, ybuf, N);
    unsigned short* xw = ybuf;

    // ---- heads ----
    heads_kernel<<<WGRID_H, TPB, 0, stream>>>(rowptr, degi, srcids, perm, xw, dinv,
                                              b_gcn, W1, b1, W2, b2, out, N);
}

// Round 3
// 303.653 us; speedup vs baseline: 1.3401x; 1.0244x over previous
//
#include <hip/hip_runtime.h>
#include <hip/hip_bf16.h>

// GCNII fused, bf16 pre-scaled activations (xs = dinv*x), src-only CSR built by
// two-pass bucket sort, 4-node-slot gather waves with 8-edge-deep load pipelining,
// degree-sorted node permutation. N=100000, E=1000000, F=64.
// This version: W/Wg MFMA A-fragments live in REGISTERS (each wave only ever
// used its own 4 fragments -> 16 scattered loads/lane at kernel start), wf/wgf
// LDS staging deleted (layer LDS 20.7KB -> 4.4KB, fused 37.4KB -> 4.4KB) to
// lift the occupancy cap (was 4 blocks/CU, 33% measured). Block-coop 16-node
// MFMA tile, v_cvt_pk_bf16_f32 everywhere, clamp-free gather.
// Output: concat(out1 [N*4], out2 [N*3], h [N*64]) fp32.
// NOTE: record packing (dst&127)<<17 | src requires N <= 131072.

#define TPB 256
#define NBSH 7    // 128 nodes per bucket
typedef __hip_bfloat16 bf16;
typedef __attribute__((ext_vector_type(8))) short short8;  // 8 bf16 = 4 VGPR
typedef __attribute__((ext_vector_type(4))) float f32x4;   // MFMA C/D frag

#define MFMA16(A, B, C) __builtin_amdgcn_mfma_f32_16x16x32_bf16((A), (B), (C), 0, 0, 0)

__device__ __forceinline__ float lo16(int u) { return __int_as_float(u << 16); }
__device__ __forceinline__ float hi16(int u) { return __int_as_float(u & 0xffff0000); }

// packed f32x2 -> bf16x2 (RNE), lo in [15:0], hi in [31:16]
__device__ __forceinline__ unsigned cvtpk(float lo, float hi) {
    unsigned r;
    asm("v_cvt_pk_bf16_f32 %0, %1, %2" : "=v"(r) : "v"(lo), "v"(hi));
    return r;
}

// ---- pass 0: bucket histogram (LDS-privatized) ----
__global__ void ebhist_kernel(const int* __restrict__ col, int* __restrict__ bh,
                              int E, int B) {
    __shared__ int lh[800];
    for (int i = threadIdx.x; i < B; i += blockDim.x) lh[i] = 0;
    __syncthreads();
    for (int e = blockIdx.x * blockDim.x + threadIdx.x; e < E; e += gridDim.x * blockDim.x)
        atomicAdd(&lh[col[e] >> NBSH], 1);
    __syncthreads();
    for (int i = threadIdx.x; i < B; i += blockDim.x) {
        int c = lh[i];
        if (c) atomicAdd(&bh[i], c);
    }
}

// ---- exclusive scan of bh -> bcur (cursors) and boff (bounds, boff[B]=E) ----
__global__ void bscan_kernel(const int* __restrict__ bh, int* __restrict__ bcur,
                             int* __restrict__ boff, int B, int E) {
    __shared__ int s[256];
    int t = threadIdx.x;
    int v[4]; int sum = 0;
#pragma unroll
    for (int i = 0; i < 4; ++i) {
        int idx = t * 4 + i;
        v[i] = (idx < B) ? bh[idx] : 0;
        sum += v[i];
    }
    s[t] = sum;
    __syncthreads();
    for (int off = 1; off < 256; off <<= 1) {
        int val = (t >= off) ? s[t - off] : 0;
        __syncthreads();
        s[t] += val;
        __syncthreads();
    }
    int run = s[t] - sum;
#pragma unroll
    for (int i = 0; i < 4; ++i) {
        int idx = t * 4 + i;
        if (idx < B) { bcur[idx] = run; boff[idx] = run; }
        run += v[i];
    }
    if (t == 255) boff[B] = E;
}

// ---- pass 1: bucket scatter with per-block range reservation ----
__global__ void bucket_scatter_kernel(const int* __restrict__ ei, int* __restrict__ bcur,
                                      unsigned int* __restrict__ ebuf, int E, int B) {
    __shared__ int lh[800], lb[800];
    int chunk = (E + gridDim.x - 1) / gridDim.x;
    int beg = blockIdx.x * chunk;
    int end = min(beg + chunk, E);
    for (int i = threadIdx.x; i < B; i += blockDim.x) lh[i] = 0;
    __syncthreads();
    for (int e = beg + threadIdx.x; e < end; e += blockDim.x)
        atomicAdd(&lh[ei[E + e] >> NBSH], 1);
    __syncthreads();
    for (int i = threadIdx.x; i < B; i += blockDim.x) {
        int c = lh[i];
        lb[i] = c ? atomicAdd(&bcur[i], c) : 0;   // one global atomic per bin per block
    }
    __syncthreads();
    for (int i = threadIdx.x; i < B; i += blockDim.x) lh[i] = 0;
    __syncthreads();
    for (int e = beg + threadIdx.x; e < end; e += blockDim.x) {
        int r = ei[e];
        int c = ei[E + e];
        int bin = c >> NBSH;
        int rank = atomicAdd(&lh[bin], 1);        // LDS rank
        ebuf[lb[bin] + rank] = ((unsigned)(c & 127) << 17) | (unsigned)r;
    }
}

// ---- pass 2: per-bucket place; also emits degi/rowptr/dinv/sdeg ----
__global__ __launch_bounds__(128) void bucket_place_kernel(
        const int* __restrict__ boff, const unsigned int* __restrict__ ebuf,
        int* __restrict__ rowptr, int* __restrict__ degi,
        float* __restrict__ dinv, float* __restrict__ sdeg,
        int* __restrict__ srcids, int n) {
    __shared__ int cnt[128], loff[128], lcur[128];
    int b = blockIdx.x;
    int t = threadIdx.x;
    int lo = boff[b];
    int hi = boff[b + 1];
    int vbase = b << NBSH;
    cnt[t] = 0;
    __syncthreads();
    for (int i = lo + t; i < hi; i += 128)
        atomicAdd(&cnt[ebuf[i] >> 17], 1);
    __syncthreads();
    int mine = cnt[t];
    loff[t] = mine;
    __syncthreads();
    for (int off = 1; off < 128; off <<= 1) {
        int val = (t >= off) ? loff[t - off] : 0;
        __syncthreads();
        loff[t] += val;
        __syncthreads();
    }
    int excl = loff[t] - mine;
    int v = vbase + t;
    if (v < n) {
        rowptr[v] = lo + excl;
        degi[v] = mine;
        float d = (float)mine + 1.0f;
        dinv[v] = rsqrtf(d);
        sdeg[v] = sqrtf(d);
    }
    lcur[t] = lo + excl;
    __syncthreads();
    for (int i = lo + t; i < hi; i += 128) {
        unsigned int r = ebuf[i];
        int pos = atomicAdd(&lcur[r >> 17], 1);
        srcids[pos] = (int)(r & 0x1FFFFu);
    }
}

// ---- degree histogram (LDS-privatized) ----
__global__ void dhist_kernel(const int* __restrict__ degi, int* __restrict__ dh, int n) {
    __shared__ int lh[256];
    lh[threadIdx.x] = 0;
    __syncthreads();
    for (int v = blockIdx.x * blockDim.x + threadIdx.x; v < n; v += gridDim.x * blockDim.x)
        atomicAdd(&lh[min(degi[v], 255)], 1);
    __syncthreads();
    int c = lh[threadIdx.x];
    if (c) atomicAdd(&dh[threadIdx.x], c);
}

__global__ void dscan_kernel(const int* __restrict__ dh, int* __restrict__ dcur) {
    __shared__ int s[256];
    int t = threadIdx.x;
    int mine = dh[t];
    s[t] = mine;
    __syncthreads();
    for (int off = 1; off < 256; off <<= 1) {
        int val = (t >= off) ? s[t - off] : 0;
        __syncthreads();
        s[t] += val;
        __syncthreads();
    }
    dcur[t] = s[t] - mine;  // exclusive
}

// ---- placement: per-block chunk, LDS hist -> bulk range reservation -> LDS rank ----
__global__ void place_kernel(const int* __restrict__ degi, int* __restrict__ dcur,
                             int* __restrict__ perm, int n) {
    __shared__ int lh[256], lb[256];
    int chunk = (n + gridDim.x - 1) / gridDim.x;
    int beg = blockIdx.x * chunk;
    int end = min(beg + chunk, n);
    lh[threadIdx.x] = 0;
    __syncthreads();
    for (int v = beg + threadIdx.x; v < end; v += blockDim.x)
        atomicAdd(&lh[min(degi[v], 255)], 1);
    __syncthreads();
    int c = lh[threadIdx.x];
    lb[threadIdx.x] = c ? atomicAdd(&dcur[threadIdx.x], c) : 0;
    __syncthreads();
    lh[threadIdx.x] = 0;
    __syncthreads();
    for (int v = beg + threadIdx.x; v < end; v += blockDim.x) {
        int bin = min(degi[v], 255);
        int r = atomicAdd(&lh[bin], 1);
        perm[lb[bin] + r] = v;
    }
}

// ---- x0s = bf16(dinv[v] * x) ----
__global__ void cvt_kernel(const float* __restrict__ x, const float* __restrict__ dinv,
                           unsigned short* __restrict__ xb, int n4) {
    int i = blockIdx.x * blockDim.x + threadIdx.x;
    if (i < n4) {
        float dv = dinv[i >> 4];
        float4 f = ((const float4*)x)[i];
        uint2 o;
        o.x = cvtpk(f.x * dv, f.y * dv);
        o.y = cvtpk(f.z * dv, f.w * dv);
        ((uint2*)xb)[i] = o;
    }
}

// ---- per-wave W A-fragments (W^T is the A operand) in REGISTERS, bf16 hi+lo.
// Lane l of wave wid holds A[m = l&15][k = (l>>4)*8 + j], j=0..7 for k-steps
// kk=0,1 -> W[kk*32 + (l>>4)*8 + j][wid*16 + (l&15)]. 16 scattered loads/lane,
// split identical to the old LDS staging (bit-exact results).
struct WFrag { short8 h0, l0, h1, l1; };
__device__ __forceinline__ WFrag load_wfrag(const float* __restrict__ W, int col, int kg) {
    union { short8 v; unsigned u[4]; } H0, L0, H1, L1;
#pragma unroll
    for (int j = 0; j < 4; ++j) {
        float w0 = W[(kg * 8 + 2 * j) * 64 + col];
        float w1 = W[(kg * 8 + 2 * j + 1) * 64 + col];
        unsigned h = cvtpk(w0, w1);
        float h0 = __uint_as_float(h << 16);
        float h1 = __uint_as_float(h & 0xffff0000u);
        H0.u[j] = h;
        L0.u[j] = cvtpk(w0 - h0, w1 - h1);
        float v0 = W[(32 + kg * 8 + 2 * j) * 64 + col];
        float v1 = W[(32 + kg * 8 + 2 * j + 1) * 64 + col];
        unsigned g = cvtpk(v0, v1);
        float g0 = __uint_as_float(g << 16);
        float g1 = __uint_as_float(g & 0xffff0000u);
        H1.u[j] = g;
        L1.u[j] = cvtpk(v0 - g0, v1 - g1);
    }
    WFrag r;
    r.h0 = H0.v; r.l0 = L0.v; r.h1 = H1.v; r.l1 = L1.v;
    return r;
}

// ---- build the B operand (t^T) fragment from an st row: 8 consecutive fp32,
// split into bf16 hi (RNE) + lo (RNE of exact residual) via v_cvt_pk_bf16_f32.
__device__ __forceinline__ void build_bfrag(const float* __restrict__ tp,
                                            short8* bh, short8* bl) {
    float4 ta = *(const float4*)tp;
    float4 tb = *(const float4*)(tp + 4);
    float tv[8] = {ta.x, ta.y, ta.z, ta.w, tb.x, tb.y, tb.z, tb.w};
    union { short8 v; unsigned u[4]; } H, L;
#pragma unroll
    for (int j = 0; j < 4; ++j) {
        unsigned h = cvtpk(tv[2 * j], tv[2 * j + 1]);
        float h0 = __uint_as_float(h << 16);
        float h1 = __uint_as_float(h & 0xffff0000u);
        H.u[j] = h;
        L.u[j] = cvtpk(tv[2 * j] - h0, tv[2 * j + 1] - h1);
    }
    *bh = H.v;
    *bl = L.v;
}

// 6-MFMA bf16x3 tile: hi*hi + lo*hi + hi*lo over 2 k-steps
__device__ __forceinline__ f32x4 mm6(const WFrag& w, short8 bh0, short8 bl0,
                                     short8 bh1, short8 bl1) {
    f32x4 ac = {0.f, 0.f, 0.f, 0.f};
    ac = MFMA16(w.h0, bh0, ac);
    ac = MFMA16(w.l0, bh0, ac);
    ac = MFMA16(w.h0, bl0, ac);
    ac = MFMA16(w.h1, bh1, ac);
    ac = MFMA16(w.l1, bh1, ac);
    ac = MFMA16(w.h1, bl1, ac);
    return ac;
}

// ---- 4-slot gather, 8-edge-deep pipeline: lane = (slot s = lane>>4, quad g = lane&15).
// All 8 srcid loads then all 8 row loads issued before the fma tree -> 8 fetches
// in flight per lane. No per-edge clamp: over-reads land in later CSR rows or the
// zeroed 64-entry pad and are masked out of the accumulation.
struct GRes { float a0, a1, a2, a3; };
__device__ __forceinline__ GRes gather8s(const int* __restrict__ srcids, int beg, int deg,
                                         int md, const unsigned short* __restrict__ xsb,
                                         int ge) {
    GRes r{0.0f, 0.0f, 0.0f, 0.0f};
    for (int i = 0; i < md; i += 8) {
        int src[8];
#pragma unroll
        for (int u = 0; u < 8; ++u)
            src[u] = srcids[beg + i + u];
        int2 q[8];
#pragma unroll
        for (int u = 0; u < 8; ++u)
            q[u] = *(const int2*)(xsb + ((unsigned)src[u] * 64u + (unsigned)ge));
#pragma unroll
        for (int u = 0; u < 8; ++u) {
            float m = (i + u < deg) ? 1.0f : 0.0f;
            r.a0 = fmaf(m, lo16(q[u].x), r.a0);
            r.a1 = fmaf(m, hi16(q[u].x), r.a1);
            r.a2 = fmaf(m, lo16(q[u].y), r.a2);
            r.a3 = fmaf(m, hi16(q[u].y), r.a3);
        }
    }
    return r;
}

__device__ __forceinline__ void st_relu4(unsigned short* p, f32x4 a, float sc) {
    uint2 o;
    o.x = cvtpk(fmaxf(a[0], 0.f) * sc, fmaxf(a[1], 0.f) * sc);
    o.y = cvtpk(fmaxf(a[2], 0.f) * sc, fmaxf(a[3], 0.f) * sc);
    *(uint2*)p = o;
}

__device__ __forceinline__ void st_plain4(unsigned short* p, f32x4 a) {
    uint2 o;
    o.x = cvtpk(a[0], a[1]);
    o.y = cvtpk(a[2], a[3]);
    *(uint2*)p = o;
}

// ---- fused GCN2Conv layer: ys_out = dinv * relu( t @ W ),
//      t = 0.9*dinv*(S + xs_self) + 0.1*sdeg*xs_self; block-coop MFMA (bf16x3).
// Wave wid computes outf [wid*16, wid*16+16) for all 16 nodes of the block tile.
__global__ __launch_bounds__(256) void layer_kernel(
        const int* __restrict__ rowptr, const int* __restrict__ degi,
        const int* __restrict__ srcids, const int* __restrict__ perm,
        const unsigned short* __restrict__ xsb, const float* __restrict__ dinv,
        const float* __restrict__ sdeg, const float* __restrict__ W,
        unsigned short* __restrict__ yb, int n) {
    __shared__ __align__(16) float st[16][68];             // 16 nodes x 64 feat (+4 pad)
    int wid = threadIdx.x >> 6;
    int lane = threadIdx.x & 63;
    int s = lane >> 4;    // gather: node slot   | matmul: k-group
    int g = lane & 15;    // gather: feature quad| matmul: node (B col / D col)
    WFrag wA = load_wfrag(W, wid * 16 + g, s);             // registers, once
    int ntile = (n + 15) >> 4;
    // reversed: high-degree tiles (end of perm) start first -> no heavy tail
    for (int tile = ntile - 1 - blockIdx.x; tile >= 0; tile -= gridDim.x) {
        int base = tile * 16;
        int vb = base + wid * 4 + s;
        int vbc = (vb < n) ? vb : n - 1;
        int v = perm[vbc];
        int beg = rowptr[v];
        int deg = degi[v];
        int md = max(deg, __shfl_xor(deg, 16));
        md = max(md, __shfl_xor(md, 32));
        GRes r = gather8s(srcids, beg, deg, md, xsb, g * 4);
        int2 qs = *(const int2*)(xsb + ((unsigned)v * 64u + (unsigned)(g * 4)));
        float xs0 = lo16(qs.x), xs1 = hi16(qs.x), xs2 = lo16(qs.y), xs3 = hi16(qs.y);
        float c9 = 0.9f * dinv[v];
        float c1 = 0.1f * sdeg[v];
        float4 t4;
        t4.x = c9 * (r.a0 + xs0) + c1 * xs0;
        t4.y = c9 * (r.a1 + xs1) + c1 * xs1;
        t4.z = c9 * (r.a2 + xs2) + c1 * xs2;
        t4.w = c9 * (r.a3 + xs3) + c1 * xs3;
        *(float4*)&st[wid * 4 + s][g * 4] = t4;
        __syncthreads();                                   // st tile complete
        // ---- MFMA: D[outf = wid*16 + s*4 + j][node = g] ----
        int vb2 = base + g;
        int v2c = perm[(vb2 < n) ? vb2 : n - 1];
        float dv2 = dinv[v2c];
        const float* strow = st[g];
        short8 bh0, bl0, bh1, bl1;
        build_bfrag(strow + s * 8,      &bh0, &bl0);
        build_bfrag(strow + 32 + s * 8, &bh1, &bl1);
        __syncthreads();                                   // st reads done (reuse next tile)
        f32x4 ac = mm6(wA, bh0, bl0, bh1, bl1);
        if (vb2 < n) {
            unsigned short* yp = yb + ((size_t)(unsigned)v2c << 6)
                               + (unsigned)(wid * 16 + s * 4);
            st_relu4(yp, ac, dv2);
        }
    }
}

// ---- last GCN2Conv layer fused with GCNConv GEMM: xw = (dinv*relu(t@W)) @ Wg ----
__global__ __launch_bounds__(256) void layer_fused_kernel(
        const int* __restrict__ rowptr, const int* __restrict__ degi,
        const int* __restrict__ srcids, const int* __restrict__ perm,
        const unsigned short* __restrict__ xsb, const float* __restrict__ dinv,
        const float* __restrict__ sdeg, const float* __restrict__ W,
        const float* __restrict__ Wg, unsigned short* __restrict__ yb, int n) {
    __shared__ __align__(16) float st[16][68];
    int wid = threadIdx.x >> 6;
    int lane = threadIdx.x & 63;
    int s = lane >> 4;
    int g = lane & 15;
    WFrag wA = load_wfrag(W,  wid * 16 + g, s);
    WFrag wG = load_wfrag(Wg, wid * 16 + g, s);
    int ntile = (n + 15) >> 4;
    for (int tile = ntile - 1 - blockIdx.x; tile >= 0; tile -= gridDim.x) {
        int base = tile * 16;
        int vb = base + wid * 4 + s;
        int vbc = (vb < n) ? vb : n - 1;
        int v = perm[vbc];
        int beg = rowptr[v];
        int deg = degi[v];
        int md = max(deg, __shfl_xor(deg, 16));
        md = max(md, __shfl_xor(md, 32));
        GRes r = gather8s(srcids, beg, deg, md, xsb, g * 4);
        int2 qs = *(const int2*)(xsb + ((unsigned)v * 64u + (unsigned)(g * 4)));
        float xs0 = lo16(qs.x), xs1 = hi16(qs.x), xs2 = lo16(qs.y), xs3 = hi16(qs.y);
        float c9 = 0.9f * dinv[v];
        float c1 = 0.1f * sdeg[v];
        float4 t4;
        t4.x = c9 * (r.a0 + xs0) + c1 * xs0;
        t4.y = c9 * (r.a1 + xs1) + c1 * xs1;
        t4.z = c9 * (r.a2 + xs2) + c1 * xs2;
        t4.w = c9 * (r.a3 + xs3) + c1 * xs3;
        *(float4*)&st[wid * 4 + s][g * 4] = t4;
        __syncthreads();                                   // (A) st tile complete
        int vb2 = base + g;
        int v2c = perm[(vb2 < n) ? vb2 : n - 1];
        float dv2 = dinv[v2c];
        const float* strow = st[g];
        // ---- matmul 1: y3s = dinv * relu(t @ W), written back to st (fp32) ----
        {
            short8 bh0, bl0, bh1, bl1;
            build_bfrag(strow + s * 8,      &bh0, &bl0);
            build_bfrag(strow + 32 + s * 8, &bh1, &bl1);
            __syncthreads();                               // (B) all B1 reads done
            f32x4 ac = mm6(wA, bh0, bl0, bh1, bl1);
            *(float4*)&st[g][wid * 16 + s * 4] = make_float4(
                fmaxf(ac[0], 0.f) * dv2, fmaxf(ac[1], 0.f) * dv2,
                fmaxf(ac[2], 0.f) * dv2, fmaxf(ac[3], 0.f) * dv2);
        }
        __syncthreads();                                   // (C) y3s writeback complete
        // ---- matmul 2: xw = y3s @ Wg (no relu, no extra scale) ----
        {
            short8 bh0, bl0, bh1, bl1;
            build_bfrag(strow + s * 8,      &bh0, &bl0);
            build_bfrag(strow + 32 + s * 8, &bh1, &bl1);
            f32x4 ac = mm6(wG, bh0, bl0, bh1, bl1);
            __syncthreads();                               // (D) B2 reads done
            if (vb2 < n) {
                unsigned short* yp = yb + ((size_t)(unsigned)v2c << 6)
                                   + (unsigned)(wid * 16 + s * 4);
                st_plain4(yp, ac);
            }
        }
    }
}

// ---- final: h = dinv*(S + xws_self) + b_gcn; out1 = h@W1+b1; out2 = h@W2+b2 ----
__global__ __launch_bounds__(256) void heads_kernel(
        const int* __restrict__ rowptr, const int* __restrict__ degi,
        const int* __restrict__ srcids, const int* __restrict__ perm,
        const unsigned short* __restrict__ xwb, const float* __restrict__ dinv,
        const float* __restrict__ bg,
        const float* __restrict__ W1, const float* __restrict__ b1,
        const float* __restrict__ W2, const float* __restrict__ b2,
        float* __restrict__ out, int n) {
    __shared__ __align__(16) float hs[4][4][64];
    __shared__ __align__(16) float whd[448];   // whd[j*64+k], j=0..6
    __shared__ float bs[8];
    int wid = threadIdx.x >> 6;
    int lane = threadIdx.x & 63;
    int s = lane >> 4;
    int g = lane & 15;
    for (int i = threadIdx.x; i < 448; i += TPB) {   // blockDim 256 < 448: loop!
        int j = i >> 6, k = i & 63;
        whd[i] = (j < 4) ? W1[k * 4 + j] : W2[k * 3 + (j - 4)];
    }
    if (threadIdx.x < 7) bs[threadIdx.x] = (threadIdx.x < 4) ? b1[threadIdx.x] : b2[threadIdx.x - 4];
    __syncthreads();
    int j = lane >> 3;
    int k0 = (lane & 7) * 8;
    int ntile = (n + 15) >> 4;
    for (int tile = ntile - 1 - blockIdx.x; tile >= 0; tile -= gridDim.x) {
        int base = tile * 16 + wid * 4;
        int vb = base + s;
        int vbc = (vb < n) ? vb : n - 1;
        int v = perm[vbc];
        int beg = rowptr[v];
        int deg = degi[v];
        int md = max(deg, __shfl_xor(deg, 16));
        md = max(md, __shfl_xor(md, 32));
        GRes r = gather8s(srcids, beg, deg, md, xwb, g * 4);
        int2 qs = *(const int2*)(xwb + ((unsigned)v * 64u + (unsigned)(g * 4)));
        float dv = dinv[v];
        float4 bq = *(const float4*)(bg + g * 4);
        float4 h4;
        h4.x = dv * (r.a0 + lo16(qs.x)) + bq.x;
        h4.y = dv * (r.a1 + hi16(qs.x)) + bq.y;
        h4.z = dv * (r.a2 + lo16(qs.y)) + bq.z;
        h4.w = dv * (r.a3 + hi16(qs.y)) + bq.w;
        if (vb < n)
            *(float4*)&out[(size_t)7 * n + (size_t)(unsigned)v * 64 + g * 4] = h4;
        *(float4*)&hs[wid][s][g * 4] = h4;
        __builtin_amdgcn_wave_barrier();
#pragma unroll
        for (int ss = 0; ss < 4; ++ss) {
            int vb2 = base + ss;
            if (vb2 >= n) break;
            int v2 = perm[vb2];
            float part = 0.0f;
            if (j < 7) {
                float4 h0 = *(const float4*)&hs[wid][ss][k0];
                float4 h1 = *(const float4*)&hs[wid][ss][k0 + 4];
                const float4* wq = (const float4*)&whd[j * 64 + k0];
                float4 w0 = wq[0], w1 = wq[1];
                part = h0.x * w0.x + h0.y * w0.y + h0.z * w0.z + h0.w * w0.w
                     + h1.x * w1.x + h1.y * w1.y + h1.z * w1.z + h1.w * w1.w;
            }
            part += __shfl_down(part, 4);
            part += __shfl_down(part, 2);
            part += __shfl_down(part, 1);
            if ((lane & 7) == 0 && j < 7) {
                float sv = bs[j] + part;
                if (j < 4) out[(size_t)v2 * 4 + j] = sv;
                else       out[(size_t)4 * n + (size_t)v2 * 3 + (j - 4)] = sv;
            }
        }
        __builtin_amdgcn_wave_barrier();
    }
}

extern "C" void kernel_launch(void* const* d_in, const int* in_sizes, int n_in,
                              void* d_out, int out_size, void* d_ws, size_t ws_size,
                              hipStream_t stream) {
    const float* x     = (const float*)d_in[0];
    const int*   ei    = (const int*)d_in[1];
    const float* Ws    = (const float*)d_in[2];
    const float* W_gcn = (const float*)d_in[3];
    const float* b_gcn = (const float*)d_in[4];
    const float* W1    = (const float*)d_in[5];
    const float* b1    = (const float*)d_in[6];
    const float* W2    = (const float*)d_in[7];
    const float* b2    = (const float*)d_in[8];
    float* out = (float*)d_out;

    const int N = in_sizes[0] / 64;
    const int E = in_sizes[1] / 2;
    const int NLAYERS = in_sizes[2] / 4096;  // L-1 = 3
    const int B = (N + 127) >> NBSH;         // node buckets of 128

    // ws layout (ints): degi[N] rowptr[N] bh[800] bcur[800] boff[800]
    //                   dh[256] dcur[256] perm[N] srcids[E+64] ebuf[E]
    // (floats): dinv[N] sdeg[N] | (ushort): x0s, bufA, bufB (N*64 each)
    int*   degi   = (int*)d_ws;
    int*   rowptr = degi + N;
    int*   bh     = rowptr + N;
    int*   bcur   = bh + 800;
    int*   boff   = bcur + 800;
    int*   dh     = boff + 800;
    int*   dcur   = dh + 256;
    int*   perm   = dcur + 256;
    int*   srcids = perm + N;
    unsigned int* ebuf = (unsigned int*)(srcids + E + 64);
    float* dinv   = (float*)(ebuf + E);
    float* sdeg   = dinv + N;
    unsigned short* x0s  = (unsigned short*)(sdeg + N);
    unsigned short* bufA = x0s + (size_t)N * 64;
    unsigned short* bufB = bufA + (size_t)N * 64;

    const int WGRID = 4096;

    // ---- CSR build: two-pass bucket sort ----
    hipMemsetAsync(bh, 0, 800 * sizeof(int), stream);
    hipMemsetAsync(dh, 0, 256 * sizeof(int), stream);
    hipMemsetAsync(srcids + E, 0, 64 * sizeof(int), stream);  // gather tail pad
    ebhist_kernel<<<120, TPB, 0, stream>>>(ei + E, bh, E, B);
    bscan_kernel<<<1, 256, 0, stream>>>(bh, bcur, boff, B, E);
    bucket_scatter_kernel<<<120, TPB, 0, stream>>>(ei, bcur, ebuf, E, B);
    bucket_place_kernel<<<B, 128, 0, stream>>>(boff, ebuf, rowptr, degi, dinv, sdeg,
                                               srcids, N);
    // ---- degree-sorted permutation ----
    dhist_kernel<<<64, 256, 0, stream>>>(degi, dh, N);
    dscan_kernel<<<1, 256, 0, stream>>>(dh, dcur);
    place_kernel<<<64, 256, 0, stream>>>(degi, dcur, perm, N);
    cvt_kernel<<<(N * 16 + TPB - 1) / TPB, TPB, 0, stream>>>(x, dinv, x0s, N * 16);

    // ---- GCN2Conv layers: first NLAYERS-1 plain, last fused with GCNConv GEMM ----
    const unsigned short* xcur = x0s;
    unsigned short* ybuf = bufA;
    for (int i = 0; i < NLAYERS - 1; ++i) {
        layer_kernel<<<WGRID, TPB, 0, stream>>>(rowptr, degi, srcids, perm, xcur,
                                                dinv, sdeg, Ws + (size_t)i * 4096, ybuf, N);
        xcur = ybuf;
        ybuf = (ybuf == bufA) ? bufB : bufA;
    }
    layer_fused_kernel<<<WGRID, TPB, 0, stream>>>(rowptr, degi, srcids, perm, xcur,
                                                  dinv, sdeg,
                                                  Ws + (size_t)(NLAYERS - 1) * 4096,
                                                  W_gcn, ybuf, N);
    unsigned short* xw = ybuf;

    // ---- heads ----
    heads_kernel<<<WGRID, TPB, 0, stream>>>(rowptr, degi, srcids, perm, xw, dinv,
                                            b_gcn, W1, b1, W2, b2, out, N);
}